// Round 4
// baseline (19.880 us; speedup 1.0000x reference)
//
#include <hip/hip_runtime.h>

typedef _Float16 half2_t __attribute__((ext_vector_type(2)));
typedef _Float16 half8_t __attribute__((ext_vector_type(8)));

constexpr int M_NODES = 4096;
constexpr int T_IN    = 24;
constexpr int HIDN    = 64;
constexpr int HOR     = 10;
constexpr int NB1     = 16;    // K1 blocks (partial sums)
constexpr int NB2     = 64;    // K2 blocks (redundant ODE + sliced write)

// tanh(x) = 1 - 2/(exp(2x)+1) with native v_exp_f32 / v_rcp_f32 (~1e-7 rel err).
__device__ __forceinline__ float fast_tanh(float x) {
    float e = __builtin_amdgcn_exp2f(x * 2.8853900817779268f);  // 2^(2*log2e*x)
    return 1.f - 2.f * __builtin_amdgcn_rcpf(e + 1.f);
}

__device__ __forceinline__ float fdot2f16(half2_t a, half2_t b, float c) {
#if __has_builtin(__builtin_amdgcn_fdot2)
    return __builtin_amdgcn_fdot2(a, b, c, false);
#else
    return fmaf((float)a[0], (float)b[0], fmaf((float)a[1], (float)b[1], c));
#endif
}

// DPP full-wave (64-lane) sum -> uniform scalar via readlane(63).
template<int CTRL, int ROW_MASK>
__device__ __forceinline__ float dpp_add(float v) {
    int t = __builtin_amdgcn_update_dpp(0, __float_as_int(v), CTRL, ROW_MASK, 0xf, true);
    return v + __int_as_float(t);
}
__device__ __forceinline__ float wave_allsum(float v) {
    v = dpp_add<0x111, 0xf>(v);   // row_shr:1
    v = dpp_add<0x112, 0xf>(v);   // row_shr:2
    v = dpp_add<0x114, 0xf>(v);   // row_shr:4
    v = dpp_add<0x118, 0xf>(v);   // row_shr:8
    v = dpp_add<0x142, 0xa>(v);   // row_bcast:15 -> rows 1,3
    v = dpp_add<0x143, 0xc>(v);   // row_bcast:31 -> rows 2,3; lane63 = total
    return __int_as_float(__builtin_amdgcn_readlane(__float_as_int(v), 63));
}

// ---- K1: 16 blocks x 256 threads; block b sums y0 over nodes [256b, 256b+256) ----
__global__ __launch_bounds__(256) void partial_sum_kernel(
    const float* __restrict__ x, float* __restrict__ partials)
{
    const int tid = threadIdx.x;
    const int n   = blockIdx.x * 256 + tid;
    float v = x[n * T_IN + (T_IN - 1)];
    float s = wave_allsum(v);
    __shared__ float ps[4];
    if ((tid & 63) == 0) ps[tid >> 6] = s;
    __syncthreads();
    if (tid == 0) partials[blockIdx.x] = (ps[0] + ps[1]) + (ps[2] + ps[3]);
}

// ---- K2: 64 blocks x 256; every block redundantly runs the ODE, writes its slice ----
__global__ __launch_bounds__(256, 1) void ode_write_kernel(
    const float* __restrict__ x, const float* __restrict__ partials,
    const float* __restrict__ W1, const float* __restrict__ b1,
    const float* __restrict__ W2, const float* __restrict__ b2,
    const float* __restrict__ W3, const float* __restrict__ b3,
    float* __restrict__ out)
{
    const int tid  = threadIdx.x;
    const int lane = tid & 63;
    const int wid  = tid >> 6;

    __shared__ float cs[HOR];
    __shared__ __align__(16) _Float16 h1h[HIDN];
    __shared__ float ys[64 + 1];   // y0 for this block's 64 nodes (+1 pad for f4 spill)

    // block's 64 output nodes: lanes 0..63 of wave 0..3 all help later; load y0 now
    const int nbase = blockIdx.x * (M_NODES / NB2);      // 64 nodes per block
    if (tid < 64) ys[tid] = x[(nbase + tid) * T_IN + (T_IN - 1)];

    if (wid == 0) {
        // weight loads issue first; latency hides under partial read
        float w2f[HIDN];
        #pragma unroll
        for (int i = 0; i < HIDN; ++i) w2f[i] = W2[i * HIDN + lane];  // column `lane`
        const float w1  = W1[lane];
        const float bb1 = b1[lane];
        const float bb2 = b2[lane];
        const float w3  = W3[lane];
        const float bb3 = b3[0];

        // mean from the 16 partials (one 64-B line, L2-hot)
        const float4* p4 = (const float4*)partials;
        float4 pa = p4[0], pb = p4[1], pc = p4[2], pd = p4[3];
        float mu = (((pa.x + pa.y) + (pa.z + pa.w)) + ((pb.x + pb.y) + (pb.z + pb.w)) +
                    ((pc.x + pc.y) + (pc.z + pc.w)) + ((pd.x + pd.y) + (pd.z + pd.w)))
                   * (1.0f / (float)M_NODES);

        half2_t w2h[HIDN / 2];
        #pragma unroll
        for (int i = 0; i < HIDN; i += 2)
            w2h[i / 2] = half2_t{(_Float16)w2f[i], (_Float16)w2f[i + 1]};

        auto feval = [&](float arg) -> float {
            float h1 = fast_tanh(arg);
            h1h[lane] = (_Float16)h1;              // wave-synchronous LDS
            __builtin_amdgcn_wave_barrier();
            const half8_t* hv = (const half8_t*)h1h;
            float acc[8];
            #pragma unroll
            for (int r = 0; r < 8; ++r) {
                half8_t u = hv[r];                 // uniform addr -> broadcast
                half2_t p0{u[0], u[1]}, p1{u[2], u[3]}, p2{u[4], u[5]}, p3{u[6], u[7]};
                float a = fdot2f16(p0, w2h[4 * r + 0], 0.f);
                a = fdot2f16(p1, w2h[4 * r + 1], a);
                a = fdot2f16(p2, w2h[4 * r + 2], a);
                acc[r] = fdot2f16(p3, w2h[4 * r + 3], a);
            }
            float h2 = fast_tanh((((acc[0] + acc[1]) + (acc[2] + acc[3])) +
                                  ((acc[4] + acc[5]) + (acc[6] + acc[7]))) + bb2);
            __builtin_amdgcn_wave_barrier();       // keep next write after reads
            return wave_allsum(h2 * w3) + bb3;
        };

        const float DT  = (float)HOR / (float)(HOR - 1);   // 10/9
        const float dw  = DT * w1;
        const float dw3 = (DT * (1.f / 3.f)) * w1;

        float c = 0.f;
        if (lane == 0) cs[0] = 0.f;
        for (int t = 1; t < HOR; ++t) {
            float base = fmaf(mu, w1, bb1);
            float k1 = feval(base);
            float k2 = feval(fmaf(k1, dw3, base));
            float k3 = feval(fmaf(k2, dw, fmaf(k1, -dw3, base)));
            float k4 = feval(fmaf(k3, dw, fmaf(k1 - k2, dw, base)));
            float d  = DT * (k1 + 3.f * k2 + 3.f * k3 + k4) * 0.125f;
            mu += d;
            c  += d;
            if (lane == 0) cs[t] = c;
        }
    }
    __syncthreads();

    // write this block's slice: 64 nodes x 10 horizons = 640 floats = 160 float4
    constexpr int NF4 = (M_NODES / NB2) * HOR / 4;   // 160
    if (tid < NF4) {
        int e = tid * 4;              // element offset within slice
        int n = e / 10;               // local node
        int h = e - n * 10;
        float4 v;
        v.x = ys[n] + cs[h]; if (++h == 10) { h = 0; ++n; }
        v.y = ys[n] + cs[h]; if (++h == 10) { h = 0; ++n; }
        v.z = ys[n] + cs[h]; if (++h == 10) { h = 0; ++n; }
        v.w = ys[n] + cs[h];
        ((float4*)(out + nbase * HOR))[tid] = v;
    }
}

extern "C" void kernel_launch(void* const* d_in, const int* in_sizes, int n_in,
                              void* d_out, int out_size, void* d_ws, size_t ws_size,
                              hipStream_t stream) {
    const float* x  = (const float*)d_in[0];
    const float* W1 = (const float*)d_in[1];
    const float* b1 = (const float*)d_in[2];
    const float* W2 = (const float*)d_in[3];
    const float* b2 = (const float*)d_in[4];
    const float* W3 = (const float*)d_in[5];
    const float* b3 = (const float*)d_in[6];
    float* out      = (float*)d_out;
    float* partials = (float*)d_ws;    // NB1 floats

    partial_sum_kernel<<<NB1, 256, 0, stream>>>(x, partials);
    ode_write_kernel<<<NB2, 256, 0, stream>>>(x, partials, W1, b1, W2, b2, W3, b3, out);
}

// Round 5
// 17.254 us; speedup vs baseline: 1.1522x; 1.1522x over previous
//
#include <hip/hip_runtime.h>

typedef _Float16 half2_t __attribute__((ext_vector_type(2)));
typedef _Float16 half8_t __attribute__((ext_vector_type(8)));

constexpr int M_NODES = 4096;
constexpr int T_IN    = 24;
constexpr int HIDN    = 64;
constexpr int HOR     = 10;
constexpr int NB      = 64;    // blocks; each owns 64 output nodes, ODE is redundant

// tanh(x) = 1 - 2/(exp(2x)+1) with native v_exp_f32 / v_rcp_f32 (~1e-7 rel err).
__device__ __forceinline__ float fast_tanh(float x) {
    float e = __builtin_amdgcn_exp2f(x * 2.8853900817779268f);  // 2^(2*log2e*x)
    return 1.f - 2.f * __builtin_amdgcn_rcpf(e + 1.f);
}

__device__ __forceinline__ float fdot2f16(half2_t a, half2_t b, float c) {
#if __has_builtin(__builtin_amdgcn_fdot2)
    return __builtin_amdgcn_fdot2(a, b, c, false);
#else
    return fmaf((float)a[0], (float)b[0], fmaf((float)a[1], (float)b[1], c));
#endif
}

// DPP full-wave (64-lane) sum -> uniform scalar via readlane(63).
template<int CTRL, int ROW_MASK>
__device__ __forceinline__ float dpp_add(float v) {
    int t = __builtin_amdgcn_update_dpp(0, __float_as_int(v), CTRL, ROW_MASK, 0xf, true);
    return v + __int_as_float(t);
}
__device__ __forceinline__ float wave_allsum(float v) {
    v = dpp_add<0x111, 0xf>(v);   // row_shr:1
    v = dpp_add<0x112, 0xf>(v);   // row_shr:2
    v = dpp_add<0x114, 0xf>(v);   // row_shr:4
    v = dpp_add<0x118, 0xf>(v);   // row_shr:8
    v = dpp_add<0x142, 0xa>(v);   // row_bcast:15 -> rows 1,3
    v = dpp_add<0x143, 0xc>(v);   // row_bcast:31 -> rows 2,3; lane63 = total
    return __int_as_float(__builtin_amdgcn_readlane(__float_as_int(v), 63));
}

__global__ __launch_bounds__(256, 1) void fused_gode_kernel(
    const float* __restrict__ x,
    const float* __restrict__ W1, const float* __restrict__ b1,
    const float* __restrict__ W2, const float* __restrict__ b2,
    const float* __restrict__ W3, const float* __restrict__ b3,
    float* __restrict__ out)
{
    const int tid  = threadIdx.x;
    const int lane = tid & 63;
    const int wid  = tid >> 6;

    __shared__ float psum[256];
    __shared__ float cs[HOR];
    __shared__ __align__(16) _Float16 h1h[HIDN];
    __shared__ float ys[64 + 1];            // this block's y0 slice

    const int nbase = blockIdx.x * (M_NODES / NB);   // 64 nodes per block

    // wave 0: issue weight loads FIRST (latency hides under the reduction)
    float w2f[HIDN];
    float w1 = 0.f, bb1 = 0.f, bb2 = 0.f, w3 = 0.f, bb3 = 0.f;
    if (wid == 0) {
        #pragma unroll
        for (int i = 0; i < HIDN; ++i) w2f[i] = W2[i * HIDN + lane];  // column `lane`
        w1  = W1[lane];
        bb1 = b1[lane];
        bb2 = b2[lane];
        w3  = W3[lane];
        bb3 = b3[0];
    }
    // wave 1: load this block's y0 slice for the write phase
    if (wid == 1) ys[lane] = x[(nbase + lane) * T_IN + (T_IN - 1)];

    // ---- redundant full reduction (identical FP order in every block) ----
    float s = 0.f;
    #pragma unroll
    for (int k = 0; k < M_NODES / 256; ++k)
        s += x[(tid + 256 * k) * T_IN + (T_IN - 1)];
    psum[tid] = s;
    __syncthreads();

    // ---- wave 0: serial scalar ODE (redundant per block, bitwise identical) ----
    if (wid == 0) {
        float t4 = psum[lane] + psum[lane + 64] + psum[lane + 128] + psum[lane + 192];
        float mu = wave_allsum(t4) * (1.0f / (float)M_NODES);

        half2_t w2h[HIDN / 2];
        #pragma unroll
        for (int i = 0; i < HIDN; i += 2)
            w2h[i / 2] = half2_t{(_Float16)w2f[i], (_Float16)w2f[i + 1]};

        auto feval = [&](float arg) -> float {
            float h1 = fast_tanh(arg);
            h1h[lane] = (_Float16)h1;              // wave-synchronous LDS
            __builtin_amdgcn_wave_barrier();
            const half8_t* hv = (const half8_t*)h1h;
            float acc[8];
            #pragma unroll
            for (int r = 0; r < 8; ++r) {
                half8_t u = hv[r];                 // uniform addr -> broadcast
                half2_t p0{u[0], u[1]}, p1{u[2], u[3]}, p2{u[4], u[5]}, p3{u[6], u[7]};
                float a = fdot2f16(p0, w2h[4 * r + 0], 0.f);
                a = fdot2f16(p1, w2h[4 * r + 1], a);
                a = fdot2f16(p2, w2h[4 * r + 2], a);
                acc[r] = fdot2f16(p3, w2h[4 * r + 3], a);
            }
            float h2 = fast_tanh((((acc[0] + acc[1]) + (acc[2] + acc[3])) +
                                  ((acc[4] + acc[5]) + (acc[6] + acc[7]))) + bb2);
            __builtin_amdgcn_wave_barrier();       // keep next write after reads
            return wave_allsum(h2 * w3) + bb3;
        };

        const float DT  = (float)HOR / (float)(HOR - 1);   // 10/9
        const float dw  = DT * w1;
        const float dw3 = (DT * (1.f / 3.f)) * w1;

        float c = 0.f;
        if (lane == 0) cs[0] = 0.f;
        for (int t = 1; t < HOR; ++t) {
            float base = fmaf(mu, w1, bb1);
            float k1 = feval(base);
            float k2 = feval(fmaf(k1, dw3, base));
            float k3 = feval(fmaf(k2, dw, fmaf(k1, -dw3, base)));
            float k4 = feval(fmaf(k3, dw, fmaf(k1 - k2, dw, base)));
            float d  = DT * (k1 + 3.f * k2 + 3.f * k3 + k4) * 0.125f;
            mu += d;
            c  += d;
            if (lane == 0) cs[t] = c;
        }
    }
    __syncthreads();

    // ---- write this block's slice: 64 nodes x 10 = 640 floats = 160 float4 ----
    constexpr int NF4 = (M_NODES / NB) * HOR / 4;   // 160
    if (tid < NF4) {
        int e = tid * 4;
        int n = e / 10;
        int h = e - n * 10;
        float4 v;
        v.x = ys[n] + cs[h]; if (++h == 10) { h = 0; ++n; }
        v.y = ys[n] + cs[h]; if (++h == 10) { h = 0; ++n; }
        v.z = ys[n] + cs[h]; if (++h == 10) { h = 0; ++n; }
        v.w = ys[n] + cs[h];
        ((float4*)(out + nbase * HOR))[tid] = v;
    }
}

extern "C" void kernel_launch(void* const* d_in, const int* in_sizes, int n_in,
                              void* d_out, int out_size, void* d_ws, size_t ws_size,
                              hipStream_t stream) {
    const float* x  = (const float*)d_in[0];
    const float* W1 = (const float*)d_in[1];
    const float* b1 = (const float*)d_in[2];
    const float* W2 = (const float*)d_in[3];
    const float* b2 = (const float*)d_in[4];
    const float* W3 = (const float*)d_in[5];
    const float* b3 = (const float*)d_in[6];
    float* out = (float*)d_out;

    fused_gode_kernel<<<NB, 256, 0, stream>>>(x, W1, b1, W2, b2, W3, b3, out);
}